// Round 1
// baseline (883.859 us; speedup 1.0000x reference)
//
#include <hip/hip_runtime.h>
#include <math.h>

#define BETA 10.0f
#define ALPHA 0.01f

// --- monotone float <-> uint code for exact order statistics ---
__device__ __forceinline__ unsigned enc_f(float f) {
    unsigned b = __float_as_uint(f);
    return b ^ ((b >> 31) ? 0xFFFFFFFFu : 0x80000000u);
}
__device__ __forceinline__ float dec_f(unsigned u) {
    unsigned b = (u & 0x80000000u) ? (u ^ 0x80000000u) : ~u;
    return __uint_as_float(b);
}
__device__ __forceinline__ float sigmoidf(float z) {
    return 1.0f / (1.0f + expf(-z));
}

// h[row] = dot(W[row, :], x)  — one wave (64 lanes) per row, float4 loads.
__global__ __launch_bounds__(256) void matvec_kernel(
    const float* __restrict__ W, const float* __restrict__ x,
    float* __restrict__ h, int nrows, int ncols4) {
    int gid  = blockIdx.x * blockDim.x + threadIdx.x;
    int wave = gid >> 6;
    int lane = threadIdx.x & 63;
    if (wave >= nrows) return;
    const float4* Wr = (const float4*)(W + (size_t)wave * (size_t)(ncols4 * 4));
    const float4* x4 = (const float4*)x;
    float acc = 0.f;
    for (int i = lane; i < ncols4; i += 64) {
        float4 w  = Wr[i];
        float4 xv = x4[i];
        acc = fmaf(w.x, xv.x, acc);
        acc = fmaf(w.y, xv.y, acc);
        acc = fmaf(w.z, xv.z, acc);
        acc = fmaf(w.w, xv.w, acc);
    }
#pragma unroll
    for (int off = 32; off > 0; off >>= 1) acc += __shfl_down(acc, off);
    if (lane == 0) h[wave] = acc;
}

// Single-block exact top-K sparsemoid.
// Binary search over 32-bit monotone codes for the K-th largest value,
// then y = sigmoid(BETA*(h - thresh)), optionally hard-masked (h < thresh -> 0).
// n must be a multiple of 256; n/256 <= 32.
__global__ __launch_bounds__(256) void topk_act_kernel(
    const float* __restrict__ h, float* __restrict__ y,
    int n, int K, int masked) {
    __shared__ int s_cnt;
    int tid = threadIdx.x;
    int m = n >> 8;  // elements per thread (32 or 16)
    unsigned codes[32];
    for (int i = 0; i < m; ++i) codes[i] = enc_f(h[tid + (i << 8)]);

    unsigned T = 0;
    for (int b = 31; b >= 0; --b) {
        unsigned cand = T | (1u << b);
        int c = 0;
        for (int i = 0; i < m; ++i) c += (codes[i] >= cand) ? 1 : 0;
#pragma unroll
        for (int off = 32; off > 0; off >>= 1) c += __shfl_down(c, off);
        if (tid == 0) s_cnt = 0;
        __syncthreads();
        if ((tid & 63) == 0) atomicAdd(&s_cnt, c);
        __syncthreads();
        if (s_cnt >= K) T = cand;
        __syncthreads();  // protect s_cnt before next iteration's reset
    }
    // T is exactly the code of the K-th largest element.
    float thresh = dec_f(T);
    for (int i = 0; i < m; ++i) {
        int idx = tid + (i << 8);
        float v = h[idx];
        float val = sigmoidf(BETA * (v - thresh));
        if (masked && codes[i] < T) val = 0.f;  // code order == float order
        y[idx] = val;
    }
}

// Fused BTSP update + lateral matvec, one block of 256 per row r:
//   Wout[r,c] = (1 - ALPHA*IS[r]) * W[r,c] + ALPHA*IS[r]*x_ca3[c]
//   h2[r]     = dot(W[r,:], x_ca3)      (uses OLD W, as in reference)
__global__ __launch_bounds__(256) void update_w_kernel(
    const float* __restrict__ W, const float* __restrict__ xca3,
    const float* __restrict__ IS, float* __restrict__ Wout,
    float* __restrict__ h2) {
    __shared__ float s_x[8192];
    __shared__ float s_part[4];
    int tid = threadIdx.x;
    int r = blockIdx.x;

    float4* sx4 = (float4*)s_x;
    const float4* x4 = (const float4*)xca3;
    for (int i = tid; i < 2048; i += 256) sx4[i] = x4[i];
    __syncthreads();

    float isr = IS[r];
    float a = 1.0f - ALPHA * isr;
    float b = ALPHA * isr;
    const float4* Wr = (const float4*)(W + (size_t)r * 8192);
    float4* Wo = (float4*)(Wout + (size_t)r * 8192);

    float acc = 0.f;
    for (int i = tid; i < 2048; i += 256) {
        float4 w  = Wr[i];
        float4 xv = sx4[i];
        float4 o;
        o.x = fmaf(a, w.x, b * xv.x);
        o.y = fmaf(a, w.y, b * xv.y);
        o.z = fmaf(a, w.z, b * xv.z);
        o.w = fmaf(a, w.w, b * xv.w);
        Wo[i] = o;
        acc = fmaf(w.x, xv.x, acc);
        acc = fmaf(w.y, xv.y, acc);
        acc = fmaf(w.z, xv.z, acc);
        acc = fmaf(w.w, xv.w, acc);
    }
#pragma unroll
    for (int off = 32; off > 0; off >>= 1) acc += __shfl_down(acc, off);
    if ((tid & 63) == 0) s_part[tid >> 6] = acc;
    __syncthreads();
    if (tid == 0) h2[r] = s_part[0] + s_part[1] + s_part[2] + s_part[3];
}

extern "C" void kernel_launch(void* const* d_in, const int* in_sizes, int n_in,
                              void* d_out, int out_size, void* d_ws, size_t ws_size,
                              hipStream_t stream) {
    const float* x_ei     = (const float*)d_in[0];  // 4096
    const float* W_ei_ca3 = (const float*)d_in[1];  // 8192 x 4096
    const float* W_ei_ca1 = (const float*)d_in[2];  // 8192 x 4096
    const float* W_ca3ca1 = (const float*)d_in[3];  // 8192 x 8192
    const float* W_ca1_eo = (const float*)d_in[4];  // 4096 x 8192

    float* out   = (float*)d_out;
    float* x_eo  = out;         // [4096]
    float* W_new = out + 4096;  // [8192*8192], 16B-aligned (4096*4 bytes offset)

    float* ws   = (float*)d_ws;
    float* h1   = ws;           // 8192
    float* h3   = ws + 8192;    // 8192
    float* xca3 = ws + 16384;   // 8192
    float* IS   = ws + 24576;   // 8192
    float* h2   = ws + 32768;   // 8192
    float* xca1 = ws + 40960;   // 8192
    float* h4   = ws + 49152;   // 4096

    // h1 = W_ei_ca3 @ x_ei ; h3 = W_ei_ca1 @ x_ei   (8192 rows x 4096 cols)
    matvec_kernel<<<2048, 256, 0, stream>>>(W_ei_ca3, x_ei, h1, 8192, 1024);
    matvec_kernel<<<2048, 256, 0, stream>>>(W_ei_ca1, x_ei, h3, 8192, 1024);
    // x_ca3 = sparsemoid(h1, K=2, masked) ; IS = sparsemoid(h3, K=100, masked)
    topk_act_kernel<<<1, 256, 0, stream>>>(h1, xca3, 8192, 2, 1);
    topk_act_kernel<<<1, 256, 0, stream>>>(h3, IS, 8192, 100, 1);
    // W_new + h2 fused (streams W_ca3_ca1 once)
    update_w_kernel<<<8192, 256, 0, stream>>>(W_ca3ca1, xca3, IS, W_new, h2);
    // x_ca1 = sparsemoid(h2, K=100, unmasked)
    topk_act_kernel<<<1, 256, 0, stream>>>(h2, xca1, 8192, 100, 0);
    // h4 = W_ca1_eo @ x_ca1   (4096 rows x 8192 cols)
    matvec_kernel<<<1024, 256, 0, stream>>>(W_ca1_eo, xca1, h4, 4096, 2048);
    // x_eo = sparsemoid(h4, K=50, masked)
    topk_act_kernel<<<1, 256, 0, stream>>>(h4, x_eo, 4096, 50, 1);
}